// Round 1
// baseline (846.108 us; speedup 1.0000x reference)
//
#include <hip/hip_runtime.h>
#include <hip/hip_bf16.h>

typedef short short8 __attribute__((ext_vector_type(8)));
typedef float f32x4 __attribute__((ext_vector_type(4)));
typedef unsigned short u16;
typedef unsigned int u32;

__device__ __forceinline__ u16 bf16rne(float f) {
    u32 u = __float_as_uint(f);
    u32 r = (u + 0x7fffu + ((u >> 16) & 1u)) >> 16;
    return (u16)r;
}
__device__ __forceinline__ float bf2f(u16 s) {
    return __uint_as_float(((u32)s) << 16);
}

// ---------------------------------------------------------------------------
// Weight prep: swizzle cg/vg weights into MFMA B-fragment order, bf16.
// Layer1: K=129 padded to 160 (5 k-tiles of 32), N=64 (4 n-tiles of 16).
// Layout: frag[nt][kt][lane][j] = W[kt*32 + (lane>>4)*8 + j][nt*16 + (lane&15)]
// ---------------------------------------------------------------------------
__global__ void prep_weights(const float* __restrict__ cgw1, const float* __restrict__ cgw2,
                             const float* __restrict__ vgw1, const float* __restrict__ vgw2,
                             u16* __restrict__ cg1s, u16* __restrict__ cg2s,
                             u16* __restrict__ vg1s, u16* __restrict__ vg2s) {
    const int total1 = 4 * 5 * 64 * 8;   // 10240
    for (int i = blockIdx.x * blockDim.x + threadIdx.x; i < total1;
         i += gridDim.x * blockDim.x) {
        int j = i & 7, lane = (i >> 3) & 63, g = i >> 9;
        int kt = g % 5, nt = g / 5;
        int k = kt * 32 + (lane >> 4) * 8 + j;
        int n = nt * 16 + (lane & 15);
        cg1s[i] = (k < 129) ? bf16rne(cgw1[k * 64 + n]) : (u16)0;
        vg1s[i] = (k < 129) ? bf16rne(vgw1[k * 64 + n]) : (u16)0;
    }
    const int total2 = 4 * 2 * 64 * 8;   // 4096
    for (int i = blockIdx.x * blockDim.x + threadIdx.x; i < total2;
         i += gridDim.x * blockDim.x) {
        int j = i & 7, lane = (i >> 3) & 63, g = i >> 9;
        int kt = g & 1, nt = g >> 1;
        int k = kt * 32 + (lane >> 4) * 8 + j;
        int n = nt * 16 + (lane & 15);
        cg2s[i] = bf16rne(cgw2[k * 64 + n]);
        vg2s[i] = bf16rne(vgw2[k * 64 + n]);
    }
}

// ---------------------------------------------------------------------------
// Input node MLP: x[KIN] -> relu -> 64 -> relu -> 64, store bf16.
// Lane-per-node; weights via uniform scalar loads.
// ---------------------------------------------------------------------------
template <int KIN>
__global__ __launch_bounds__(256) void node_mlp_in(
    const float* __restrict__ x, int n_nodes,
    const float* __restrict__ w1, const float* __restrict__ b1,
    const float* __restrict__ w2, const float* __restrict__ b2,
    u16* __restrict__ outbf) {
    int n = blockIdx.x * 256 + threadIdx.x;
    bool act = n < n_nodes;
    long nn = act ? n : 0;
    float xr[KIN];
#pragma unroll
    for (int k = 0; k < KIN; k++) xr[k] = x[nn * KIN + k];
    float h[64];
#pragma unroll
    for (int j = 0; j < 64; j++) h[j] = b1[j];
    for (int k = 0; k < KIN; k++) {
        float xk = xr[k];
#pragma unroll
        for (int j = 0; j < 64; j++) h[j] = fmaf(xk, w1[k * 64 + j], h[j]);
    }
    float o[64];
#pragma unroll
    for (int j = 0; j < 64; j++) o[j] = b2[j];
    for (int k = 0; k < 64; k++) {
        float xk = fmaxf(h[k], 0.f);
#pragma unroll
        for (int j = 0; j < 64; j++) o[j] = fmaf(xk, w2[k * 64 + j], o[j]);
    }
    if (act) {
        u32* op = (u32*)(outbf + (size_t)n * 64);
#pragma unroll
        for (int j = 0; j < 64; j += 2) {
            u32 lo = bf16rne(fmaxf(o[j], 0.f));
            u32 hi = bf16rne(fmaxf(o[j + 1], 0.f));
            op[j >> 1] = lo | (hi << 16);
        }
    }
}

// ---------------------------------------------------------------------------
// Edge conv: per 64-edge tile, gather concat(u[uidx],v[vidx],e_val) as bf16
// into LDS, 2-layer MLP via mfma_f32_16x16x32_bf16, atomicAdd into agg[uidx].
// ---------------------------------------------------------------------------
#define AROW 168   // 160 K-pad + 8 bank-pad (bf16 elems, 16B-multiple)
#define HROW 72

__global__ __launch_bounds__(256, 2) void edge_conv(
    const u16* __restrict__ u_feat, const u16* __restrict__ v_feat,
    const int* __restrict__ u_idx, const int* __restrict__ v_idx,
    const float* __restrict__ e_val,
    const u16* __restrict__ w1s, const u16* __restrict__ w2s,
    const float* __restrict__ b1, const float* __restrict__ b2,
    float* __restrict__ agg, int n_tiles) {
    __shared__ __align__(16) u16 A[64 * AROW];
    __shared__ __align__(16) u16 Hs[4][16 * HROW];
    __shared__ int Su[64], Sv[64];
    __shared__ float Sev[64];

    int tid = threadIdx.x;
    int lane = tid & 63;
    int w = tid >> 6;
    int l15 = lane & 15, lq = lane >> 4;

    // zero the K-pad columns (129..167) once; never rewritten afterwards
    for (int i = tid; i < 64 * (AROW - 129); i += 256) {
        int r = i / (AROW - 129);
        int cc = 129 + (i - r * (AROW - 129));
        A[r * AROW + cc] = 0;
    }

    // B fragments resident in registers for the whole kernel
    short8 w1f[4][5], w2f[4][2];
#pragma unroll
    for (int nt = 0; nt < 4; nt++) {
#pragma unroll
        for (int kt = 0; kt < 5; kt++)
            w1f[nt][kt] = *(const short8*)(w1s + ((nt * 5 + kt) * 64 + lane) * 8);
#pragma unroll
        for (int kt = 0; kt < 2; kt++)
            w2f[nt][kt] = *(const short8*)(w2s + ((nt * 2 + kt) * 64 + lane) * 8);
    }
    float b1v[4], b2v[4];
#pragma unroll
    for (int nt = 0; nt < 4; nt++) {
        b1v[nt] = b1[nt * 16 + l15];
        b2v[nt] = b2[nt * 16 + l15];
    }
    __syncthreads();

    for (int tile = blockIdx.x; tile < n_tiles; tile += gridDim.x) {
        if (tid < 64) {
            int e = tile * 64 + tid;
            Su[tid] = u_idx[e];
            Sv[tid] = v_idx[e];
            Sev[tid] = e_val[e];
        }
        __syncthreads();
        // gather: 64 edges x 16 chunks of 16B (8 u-chunks + 8 v-chunks)
#pragma unroll
        for (int t = 0; t < 4; t++) {
            int cid = tid + t * 256;
            int e = cid >> 4, cch = cid & 15;
            const u16* src = (cch < 8)
                ? (u_feat + (size_t)Su[e] * 64 + cch * 8)
                : (v_feat + (size_t)Sv[e] * 64 + (cch - 8) * 8);
            uint4 d = *(const uint4*)src;
            int col = (cch < 8) ? cch * 8 : 64 + (cch - 8) * 8;
            *(uint4*)(&A[e * AROW + col]) = d;
        }
        if (tid < 64) A[tid * AROW + 128] = bf16rne(Sev[tid]);
        __syncthreads();

        // ---- layer 1: [64x160] @ [160x64] ----
        short8 a1[5];
#pragma unroll
        for (int kt = 0; kt < 5; kt++)
            a1[kt] = *(const short8*)(&A[(w * 16 + l15) * AROW + kt * 32 + lq * 8]);
        u16* Hw = &Hs[w][0];
#pragma unroll
        for (int nt = 0; nt < 4; nt++) {
            f32x4 acc = {0.f, 0.f, 0.f, 0.f};
#pragma unroll
            for (int kt = 0; kt < 5; kt++)
                acc = __builtin_amdgcn_mfma_f32_16x16x32_bf16(a1[kt], w1f[nt][kt], acc, 0, 0, 0);
#pragma unroll
            for (int r = 0; r < 4; r++) {
                float hv = fmaxf(acc[r] + b1v[nt], 0.f);
                Hw[(lq * 4 + r) * HROW + nt * 16 + l15] = bf16rne(hv);
            }
        }
        // ---- layer 2: [16x64] @ [64x64] per wave ----
        short8 a2[2];
#pragma unroll
        for (int kt = 0; kt < 2; kt++)
            a2[kt] = *(const short8*)(&Hw[l15 * HROW + kt * 32 + lq * 8]);
        int ur[4];
#pragma unroll
        for (int r = 0; r < 4; r++) ur[r] = Su[w * 16 + lq * 4 + r];
#pragma unroll
        for (int nt = 0; nt < 4; nt++) {
            f32x4 acc = {0.f, 0.f, 0.f, 0.f};
#pragma unroll
            for (int kt = 0; kt < 2; kt++)
                acc = __builtin_amdgcn_mfma_f32_16x16x32_bf16(a2[kt], w2f[nt][kt], acc, 0, 0, 0);
#pragma unroll
            for (int r = 0; r < 4; r++) {
                float gv = fmaxf(acc[r] + b2v[nt], 0.f);
                __hip_atomic_fetch_add(&agg[(size_t)ur[r] * 64 + nt * 16 + l15], gv,
                                       __ATOMIC_RELAXED, __HIP_MEMORY_SCOPE_AGENT);
            }
        }
        __syncthreads();
    }
}

// ---------------------------------------------------------------------------
// f-MLP: concat(u_bf16[64], agg_f32[64]) -> 64 -> 64, store bf16 (c-side).
// ---------------------------------------------------------------------------
__global__ __launch_bounds__(256) void node_mlp_f(
    const u16* __restrict__ ubf, const float* __restrict__ agg, int n_nodes,
    const float* __restrict__ w1, const float* __restrict__ b1,
    const float* __restrict__ w2, const float* __restrict__ b2,
    u16* __restrict__ outbf) {
    int n = blockIdx.x * 256 + threadIdx.x;
    bool act = n < n_nodes;
    long nn = act ? n : 0;
    float h[64];
#pragma unroll
    for (int j = 0; j < 64; j++) h[j] = b1[j];
    for (int k = 0; k < 64; k++) {
        float xk = bf2f(ubf[nn * 64 + k]);
#pragma unroll
        for (int j = 0; j < 64; j++) h[j] = fmaf(xk, w1[k * 64 + j], h[j]);
    }
    for (int k = 0; k < 64; k++) {
        float xk = agg[nn * 64 + k];
#pragma unroll
        for (int j = 0; j < 64; j++) h[j] = fmaf(xk, w1[(64 + k) * 64 + j], h[j]);
    }
    float o[64];
#pragma unroll
    for (int j = 0; j < 64; j++) o[j] = b2[j];
    for (int k = 0; k < 64; k++) {
        float xk = fmaxf(h[k], 0.f);
#pragma unroll
        for (int j = 0; j < 64; j++) o[j] = fmaf(xk, w2[k * 64 + j], o[j]);
    }
    if (act) {
        u32* op = (u32*)(outbf + (size_t)n * 64);
#pragma unroll
        for (int j = 0; j < 64; j += 2) {
            u32 lo = bf16rne(fmaxf(o[j], 0.f));
            u32 hi = bf16rne(fmaxf(o[j + 1], 0.f));
            op[j >> 1] = lo | (hi << 16);
        }
    }
}

// ---------------------------------------------------------------------------
// v-side f-MLP fused with tail: concat(v1,agg)->64->64 (=v2), then
// relu(v2@tw1+tb1)@tw2+tb2 -> sigmoid -> out[NV,8] f32.
// ---------------------------------------------------------------------------
__global__ __launch_bounds__(256) void node_mlp_vf_tail(
    const u16* __restrict__ vbf, const float* __restrict__ agg, int n_nodes,
    const float* __restrict__ w1, const float* __restrict__ b1,
    const float* __restrict__ w2, const float* __restrict__ b2,
    const float* __restrict__ tw1, const float* __restrict__ tb1,
    const float* __restrict__ tw2, const float* __restrict__ tb2,
    float* __restrict__ out) {
    int n = blockIdx.x * 256 + threadIdx.x;
    bool act = n < n_nodes;
    long nn = act ? n : 0;
    float h[64];
#pragma unroll
    for (int j = 0; j < 64; j++) h[j] = b1[j];
    for (int k = 0; k < 64; k++) {
        float xk = bf2f(vbf[nn * 64 + k]);
#pragma unroll
        for (int j = 0; j < 64; j++) h[j] = fmaf(xk, w1[k * 64 + j], h[j]);
    }
    for (int k = 0; k < 64; k++) {
        float xk = agg[nn * 64 + k];
#pragma unroll
        for (int j = 0; j < 64; j++) h[j] = fmaf(xk, w1[(64 + k) * 64 + j], h[j]);
    }
    float o[64];  // v2 pre-relu
#pragma unroll
    for (int j = 0; j < 64; j++) o[j] = b2[j];
    for (int k = 0; k < 64; k++) {
        float xk = fmaxf(h[k], 0.f);
#pragma unroll
        for (int j = 0; j < 64; j++) o[j] = fmaf(xk, w2[k * 64 + j], o[j]);
    }
    // tail layer 1 (reuse h)
#pragma unroll
    for (int j = 0; j < 64; j++) h[j] = tb1[j];
    for (int k = 0; k < 64; k++) {
        float xk = fmaxf(o[k], 0.f);
#pragma unroll
        for (int j = 0; j < 64; j++) h[j] = fmaf(xk, tw1[k * 64 + j], h[j]);
    }
    // tail layer 2 -> K=8 + sigmoid
    float s[8];
#pragma unroll
    for (int j = 0; j < 8; j++) s[j] = tb2[j];
    for (int k = 0; k < 64; k++) {
        float xk = fmaxf(h[k], 0.f);
#pragma unroll
        for (int j = 0; j < 8; j++) s[j] = fmaf(xk, tw2[k * 8 + j], s[j]);
    }
    if (act) {
        float4 r0, r1;
        r0.x = 1.f / (1.f + __expf(-s[0]));
        r0.y = 1.f / (1.f + __expf(-s[1]));
        r0.z = 1.f / (1.f + __expf(-s[2]));
        r0.w = 1.f / (1.f + __expf(-s[3]));
        r1.x = 1.f / (1.f + __expf(-s[4]));
        r1.y = 1.f / (1.f + __expf(-s[5]));
        r1.z = 1.f / (1.f + __expf(-s[6]));
        r1.w = 1.f / (1.f + __expf(-s[7]));
        float4* op = (float4*)(out + (size_t)n * 8);
        op[0] = r0;
        op[1] = r1;
    }
}

extern "C" void kernel_launch(void* const* d_in, const int* in_sizes, int n_in,
                              void* d_out, int out_size, void* d_ws, size_t ws_size,
                              hipStream_t stream) {
    const float* v        = (const float*)d_in[0];
    const float* c        = (const float*)d_in[1];
    const int*   cons_idx = (const int*)d_in[2];
    const int*   var_idx  = (const int*)d_in[3];
    const float* e_val    = (const float*)d_in[4];
    const float* ev_w1 = (const float*)d_in[5],  *ev_b1 = (const float*)d_in[6];
    const float* ev_w2 = (const float*)d_in[7],  *ev_b2 = (const float*)d_in[8];
    const float* ec_w1 = (const float*)d_in[9],  *ec_b1 = (const float*)d_in[10];
    const float* ec_w2 = (const float*)d_in[11], *ec_b2 = (const float*)d_in[12];
    const float* cg_w1 = (const float*)d_in[13], *cg_b1 = (const float*)d_in[14];
    const float* cg_w2 = (const float*)d_in[15], *cg_b2 = (const float*)d_in[16];
    const float* cf_w1 = (const float*)d_in[17], *cf_b1 = (const float*)d_in[18];
    const float* cf_w2 = (const float*)d_in[19], *cf_b2 = (const float*)d_in[20];
    const float* vg_w1 = (const float*)d_in[21], *vg_b1 = (const float*)d_in[22];
    const float* vg_w2 = (const float*)d_in[23], *vg_b2 = (const float*)d_in[24];
    const float* vf_w1 = (const float*)d_in[25], *vf_b1 = (const float*)d_in[26];
    const float* vf_w2 = (const float*)d_in[27], *vf_b2 = (const float*)d_in[28];
    const float* t_w1  = (const float*)d_in[29], *t_b1  = (const float*)d_in[30];
    const float* t_w2  = (const float*)d_in[31], *t_b2  = (const float*)d_in[32];

    const int NV = in_sizes[0] / 19;
    const int NC = in_sizes[1] / 5;
    const int NE = in_sizes[4];

    char* ws = (char*)d_ws;
    size_t off = 0;
    u16* v1bf = (u16*)(ws + off); off += (size_t)NV * 64 * 2;
    u16* c1bf = (u16*)(ws + off); off += (size_t)NC * 64 * 2;
    u16* c2bf = (u16*)(ws + off); off += (size_t)NC * 64 * 2;
    float* agg_c = (float*)(ws + off); off += (size_t)NC * 64 * 4;
    float* agg_v = (float*)(ws + off); off += (size_t)NV * 64 * 4;
    u16* cg1s = (u16*)(ws + off); off += 10240 * 2;
    u16* cg2s = (u16*)(ws + off); off += 4096 * 2;
    u16* vg1s = (u16*)(ws + off); off += 10240 * 2;
    u16* vg2s = (u16*)(ws + off); off += 4096 * 2;

    prep_weights<<<40, 256, 0, stream>>>(cg_w1, cg_w2, vg_w1, vg_w2,
                                         cg1s, cg2s, vg1s, vg2s);
    node_mlp_in<19><<<(NV + 255) / 256, 256, 0, stream>>>(
        v, NV, ev_w1, ev_b1, ev_w2, ev_b2, v1bf);
    node_mlp_in<5><<<(NC + 255) / 256, 256, 0, stream>>>(
        c, NC, ec_w1, ec_b1, ec_w2, ec_b2, c1bf);

    hipMemsetAsync(agg_c, 0, (size_t)NC * 64 * 4, stream);
    edge_conv<<<512, 256, 0, stream>>>(c1bf, v1bf, cons_idx, var_idx, e_val,
                                       cg1s, cg2s, cg_b1, cg_b2, agg_c, NE / 64);
    node_mlp_f<<<(NC + 255) / 256, 256, 0, stream>>>(
        c1bf, agg_c, NC, cf_w1, cf_b1, cf_w2, cf_b2, c2bf);

    hipMemsetAsync(agg_v, 0, (size_t)NV * 64 * 4, stream);
    edge_conv<<<512, 256, 0, stream>>>(v1bf, c2bf, var_idx, cons_idx, e_val,
                                       vg1s, vg2s, vg_b1, vg_b2, agg_v, NE / 64);
    node_mlp_vf_tail<<<(NV + 255) / 256, 256, 0, stream>>>(
        v1bf, agg_v, NV, vf_w1, vf_b1, vf_w2, vf_b2,
        t_w1, t_b1, t_w2, t_b2, (float*)d_out);
}